// Round 1
// baseline (368.540 us; speedup 1.0000x reference)
//
#include <hip/hip_runtime.h>
#include <math.h>

#define BATCH 512

__device__ __forceinline__ float elu1(float v) {
    return v > 0.f ? v : expm1f(v);
}

// -------- Kernel 1: conv1 (collapsed spline = 3x3 stencil) + ELU + 2x2 maxpool
// x: [B,28,28] (Cin=1), W1: [25][1][32], root1: [32], b1: [32]
// out p1: [B,14,14,32]
__global__ __launch_bounds__(256) void k1_conv1_pool(
    const float* __restrict__ x, const float* __restrict__ W1,
    const float* __restrict__ root1, const float* __restrict__ b1,
    float* __restrict__ p1) {
    int t = blockIdx.x * 256 + threadIdx.x;
    const int total = BATCH * 14 * 14;
    if (t >= total) return;
    int px = t % 14, py = (t / 14) % 14, b = t / 196;
    const float* xb = x + b * 784;

    float mx[32];
    #pragma unroll
    for (int c = 0; c < 32; ++c) mx[c] = -1e30f;

    #pragma unroll
    for (int sy = 0; sy < 2; ++sy)
    #pragma unroll
    for (int sx = 0; sx < 2; ++sx) {
        int y = py * 2 + sy, xx = px * 2 + sx;
        float xc = xb[y * 28 + xx];
        float acc[32];
        #pragma unroll
        for (int c = 0; c < 32; ++c) acc[c] = 0.f;
        int deg = 0;
        #pragma unroll
        for (int dy = -1; dy <= 1; ++dy)
        #pragma unroll
        for (int dx = -1; dx <= 1; ++dx) {
            if (dy == 0 && dx == 0) continue;
            int ny = y + dy, nx = xx + dx;
            if (ny < 0 || ny >= 28 || nx < 0 || nx >= 28) continue;
            ++deg;
            float xv = xb[ny * 28 + nx];
            const float* w = W1 + (2 * (dx + 1) + 10 * (dy + 1)) * 32;
            #pragma unroll
            for (int c = 0; c < 32; ++c) acc[c] += xv * w[c];
        }
        float inv = 1.f / (float)deg;
        #pragma unroll
        for (int c = 0; c < 32; ++c) {
            float v = acc[c] * inv + xc * root1[c] + b1[c];
            mx[c] = fmaxf(mx[c], elu1(v));
        }
    }
    float4* out4 = (float4*)(p1 + (size_t)t * 32);
    #pragma unroll
    for (int q = 0; q < 8; ++q)
        out4[q] = make_float4(mx[4 * q], mx[4 * q + 1], mx[4 * q + 2], mx[4 * q + 3]);
}

// -------- Kernel 2: conv2 (3x3 stencil, 32->64) + ELU + 2x2 maxpool
// p1: [B,14,14,32], W2: [25][32][64], root2: [32][64], b2: [64]
// out p2: [B,7,7,64]  (= [B,3136] in reference order)
// One block (256 thr) per pooled cell: 4 positions x 64 channels.
__global__ __launch_bounds__(256) void k2_conv2_pool(
    const float* __restrict__ p1, const float* __restrict__ W2,
    const float* __restrict__ root2, const float* __restrict__ b2,
    float* __restrict__ p2) {
    __shared__ float patch[4][4][32];
    __shared__ float red[4][64];
    int blk = blockIdx.x;
    int px2 = blk % 7, py2 = (blk / 7) % 7, b = blk / 49;
    int tid = threadIdx.x;

    // stage 4x4 node patch (rows 2*py2-1 .. 2*py2+2), OOB -> 0
    #pragma unroll
    for (int l = tid; l < 512; l += 256) {
        int c = l & 31, ix = (l >> 5) & 3, iy = l >> 7;
        int gy = 2 * py2 - 1 + iy, gx = 2 * px2 - 1 + ix;
        float v = 0.f;
        if (gy >= 0 && gy < 14 && gx >= 0 && gx < 14)
            v = p1[(((size_t)b * 14 + gy) * 14 + gx) * 32 + c];
        patch[iy][ix][c] = v;
    }
    __syncthreads();

    int o = tid & 63, pos = tid >> 6;
    int sy = pos >> 1, sx = pos & 1;
    int y = 2 * py2 + sy, x = 2 * px2 + sx;

    float acc = 0.f;
    int deg = 0;
    #pragma unroll
    for (int dy = -1; dy <= 1; ++dy)
    #pragma unroll
    for (int dx = -1; dx <= 1; ++dx) {
        if (dy == 0 && dx == 0) continue;
        int ny = y + dy, nx = x + dx;
        if (ny < 0 || ny >= 14 || nx < 0 || nx >= 14) continue;
        ++deg;
        const float* pv = patch[sy + 1 + dy][sx + 1 + dx];
        const float* w = W2 + (size_t)(2 * (dx + 1) + 10 * (dy + 1)) * 2048 + o;
        float a = 0.f;
        #pragma unroll
        for (int i = 0; i < 32; ++i) a += pv[i] * w[(size_t)i * 64];
        acc += a;
    }
    float racc = 0.f;
    {
        const float* pv = patch[sy + 1][sx + 1];
        #pragma unroll
        for (int i = 0; i < 32; ++i) racc += pv[i] * root2[(size_t)i * 64 + o];
    }
    float v = acc / (float)deg + racc + b2[o];
    red[pos][o] = elu1(v);
    __syncthreads();
    if (pos == 0) {
        float m = fmaxf(fmaxf(red[0][o], red[1][o]), fmaxf(red[2][o], red[3][o]));
        p2[((size_t)b * 49 + py2 * 7 + px2) * 64 + o] = m;
    }
}

// -------- Kernel 3: fc1 [512,3136] @ [3136,512] + bias, ELU
__global__ __launch_bounds__(256) void k3_fc1(
    const float* __restrict__ a, const float* __restrict__ w,
    const float* __restrict__ bias, float* __restrict__ out) {
    __shared__ float row[3136];
    int b = blockIdx.y;
    int o = blockIdx.x * 256 + threadIdx.x;
    for (int k = threadIdx.x; k < 3136; k += 256) row[k] = a[(size_t)b * 3136 + k];
    __syncthreads();
    float acc = 0.f;
    for (int k = 0; k < 3136; ++k) acc += row[k] * w[(size_t)k * 512 + o];
    out[(size_t)b * 512 + o] = elu1(acc + bias[o]);
}

// -------- Kernel 4: fc2 (512->10) + ELU + log_softmax; one thread per batch row
__global__ __launch_bounds__(64) void k4_fc2_lsm(
    const float* __restrict__ h, const float* __restrict__ w,
    const float* __restrict__ bias, float* __restrict__ out) {
    int b = blockIdx.x * 64 + threadIdx.x;
    float acc[10];
    #pragma unroll
    for (int o = 0; o < 10; ++o) acc[o] = bias[o];
    for (int k = 0; k < 512; ++k) {
        float hv = h[(size_t)b * 512 + k];
        #pragma unroll
        for (int o = 0; o < 10; ++o) acc[o] += hv * w[k * 10 + o];
    }
    float m = -1e30f;
    #pragma unroll
    for (int o = 0; o < 10; ++o) { acc[o] = elu1(acc[o]); m = fmaxf(m, acc[o]); }
    float s = 0.f;
    #pragma unroll
    for (int o = 0; o < 10; ++o) s += expf(acc[o] - m);
    float lse = m + logf(s);
    #pragma unroll
    for (int o = 0; o < 10; ++o) out[(size_t)b * 10 + o] = acc[o] - lse;
}

extern "C" void kernel_launch(void* const* d_in, const int* in_sizes, int n_in,
                              void* d_out, int out_size, void* d_ws, size_t ws_size,
                              hipStream_t stream) {
    const float* x     = (const float*)d_in[0];
    const float* W1    = (const float*)d_in[3];
    const float* root1 = (const float*)d_in[4];
    const float* b1v   = (const float*)d_in[5];
    const float* W2    = (const float*)d_in[6];
    const float* root2 = (const float*)d_in[7];
    const float* b2v   = (const float*)d_in[8];
    const float* fc1w  = (const float*)d_in[9];
    const float* fc1b  = (const float*)d_in[10];
    const float* fc2w  = (const float*)d_in[11];
    const float* fc2b  = (const float*)d_in[12];

    float* ws = (float*)d_ws;
    float* p1 = ws;                                   // 512*196*32 = 3,211,264 f
    float* p2 = p1 + (size_t)BATCH * 196 * 32;        // 512*49*64  = 1,605,632 f
    float* h3 = p2 + (size_t)BATCH * 49 * 64;         // 512*512    =   262,144 f

    k1_conv1_pool<<<dim3((BATCH * 196 + 255) / 256), 256, 0, stream>>>(x, W1, root1, b1v, p1);
    k2_conv2_pool<<<dim3(BATCH * 49), 256, 0, stream>>>(p1, W2, root2, b2v, p2);
    k3_fc1<<<dim3(2, BATCH), 256, 0, stream>>>(p2, fc1w, fc1b, h3);
    k4_fc2_lsm<<<dim3(8), 64, 0, stream>>>(h3, fc2w, fc2b, (float*)d_out);
}